// Round 24
// baseline (243.830 us; speedup 1.0000x reference)
//
#include <hip/hip_runtime.h>

#define BB 4
#define HH 8
#define LL 8192
#define NN (BB*LL)
#define DDIM 32
#define MM 128

// ws layout (float offsets)
#define CTXR_OFF 0                          // 32*8*128*4 = 131072
#define KSUMR_OFF (CTXR_OFF + 32*8*MM*4)    // 4096
#define VSUM_OFF  (KSUMR_OFF + 32*MM)       // 1024
#define GMAX_OFF  (VSUM_OFF + 32*32)        // 1
#define ZERO_FLOATS (GMAX_OFF + 1)

#define DN 0.42044820762685725f             // 32^-0.25
#define RATIO 0.08838834764831845f          // 128^-0.5
#define EPSF 1e-4f

__device__ __forceinline__ float rl(float x, int l) {
    return __uint_as_float(__builtin_amdgcn_readlane(__float_as_uint(x), l));
}
__device__ __forceinline__ float rl4(float4 v, int c, int l) {
    const float x = (c==0) ? v.x : (c==1) ? v.y : (c==2) ? v.z : v.w;
    return rl(x, l);
}

// ------- k1: R14 readlane kernel (VALU-bound, 60% busy at 2 waves/SIMD,
// 155us solo) + R20 m-split (grid 2048, atomics constant). Rationale: R14's
// 40% idle is issue starvation; 8 blocks/CU -> 4 waves/SIMD fills it.
// (R15's grid test was confounded by simultaneous pairing change.)
// Block = (bh, chunk, mhalf); 4 waves x 64 rows; LDS tree combine.
__global__ __launch_bounds__(256, 2) void k_ctx1(const float* __restrict__ kk0,
                                                 const float* __restrict__ kk1,
                                                 const float* __restrict__ v0,
                                                 const float* __restrict__ v1,
                                                 const float* __restrict__ w,
                                                 float* __restrict__ ws) {
    __shared__ float red[2][64][34];
    const int tid = threadIdx.x;
    const int lane = tid & 63;
    const int wv  = __builtin_amdgcn_readfirstlane(tid >> 6);  // 0..3
    const int bh = blockIdx.x >> 6;
    const int chunk = (blockIdx.x >> 1) & 31;
    const int mhalf = blockIdx.x & 1;
    const int m = mhalf*64 + lane;
    const int b = bh >> 3, h = bh & 7;
    const int n0 = b*LL + chunk*256 + wv*64;    // this wave's 64 rows
    float wreg[32];                              // w * DN
    {
        const float4* w4 = (const float4*)(w + m*DDIM);
#pragma unroll
        for (int q = 0; q < 8; ++q) {
            const float4 t = w4[q];
            wreg[q*4+0]=t.x*DN; wreg[q*4+1]=t.y*DN;
            wreg[q*4+2]=t.z*DN; wreg[q*4+3]=t.w*DN;
        }
    }
    // static per-lane load offsets (in floats), within a 32-row batch
    const int rowA = lane >> 1, qA = lane & 1;            // k0/v0: 32 rows x 2 lanes
    const int offA = rowA*64 + h*8 + qA*4;
    const int rowB = lane >> 3, qB = lane & 7;            // k1/v1: 8 rows x 8 lanes
    const int offB = rowB*192 + h*24 + ((qB < 6) ? qB*4 : 20);
    float acc[32];
#pragma unroll
    for (int i = 0; i < 32; ++i) acc[i] = 0.f;
    float ksum_acc = 0.f, vsum_acc = 0.f, wmax = -3.4e38f;
#pragma unroll 1
    for (int bi = 0; bi < 2; ++bi) {
        const int nb = n0 + bi*32;
        // ---- batch loads: 10 coalesced dwordx4, all in flight together ----
        const float4 k0b = *(const float4*)(kk0 + (size_t)nb*64 + offA);
        const float4 v0b = *(const float4*)(v0  + (size_t)nb*64 + offA);
        float4 k1b[4], v1b[4];
#pragma unroll
        for (int j = 0; j < 4; ++j) {
            k1b[j] = *(const float4*)(kk1 + (size_t)nb*192 + j*1536 + offB);
            v1b[j] = *(const float4*)(v1  + (size_t)nb*192 + j*1536 + offB);
        }
        // ---- diag for 32 rows (two 16-row passes) ----
        float diagv0, diagv1;
#pragma unroll
        for (int dp = 0; dp < 2; ++dp) {
            const int dr_ = lane >> 2, dq = lane & 3;
            const int n = nb + dp*16 + dr_;
            float4 da, db;
            if (dq == 0) {
                da = *(const float4*)(kk0 + (size_t)n*64 + h*8);
                db = *(const float4*)(kk0 + (size_t)n*64 + h*8 + 4);
            } else {
                const float* bp = kk1 + (size_t)n*192 + h*24 + (dq-1)*8;
                da = *(const float4*)bp; db = *(const float4*)(bp + 4);
            }
            float ss = da.x*da.x+da.y*da.y+da.z*da.z+da.w*da.w
                     + db.x*db.x+db.y*db.y+db.z*db.z+db.w*db.w;
            ss += __shfl_xor(ss, 1); ss += __shfl_xor(ss, 2);
            const float dv_ = 0.5f*DN*DN*ss;
            if (dp == 0) diagv0 = dv_; else diagv1 = dv_;
        }
        // ---- vsum (mhalf==0 blocks, every wave its own rows) ----
        if (mhalf == 0) {
            const int ve = lane & 31, vg = lane >> 5;
#pragma unroll
            for (int dp = 0; dp < 2; ++dp)
#pragma unroll
                for (int rr = 0; rr < 8; ++rr) {
                    const int n = nb + dp*16 + vg*8 + rr;
                    vsum_acc += (ve < 8) ? v0[(size_t)n*64 + h*8 + ve]
                                         : v1[(size_t)n*192 + h*24 + (ve-8)];
                }
        }
        // ---- consume 32 rows via readlane broadcasts ----
#pragma unroll
        for (int rq = 0; rq < 4; ++rq) {
#pragma unroll
            for (int rr = 0; rr < 8; ++rr) {
                const int r = rq*8 + rr;
                const float dg = rl((r < 16) ? diagv0 : diagv1, (r & 15)*4);
                float dd0 = 0.f, dd1 = 0.f;
#pragma unroll
                for (int d = 0; d < 8; ++d) {
                    const float s = rl4(k0b, d & 3, r*2 + (d >> 2));
                    if (d & 1) dd1 = fmaf(s, wreg[d], dd1);
                    else       dd0 = fmaf(s, wreg[d], dd0);
                }
#pragma unroll
                for (int e = 0; e < 24; ++e) {
                    const float s = rl4(k1b[rq], e & 3, rr*8 + (e >> 2));
                    if (e & 1) dd1 = fmaf(s, wreg[8+e], dd1);
                    else       dd0 = fmaf(s, wreg[8+e], dd0);
                }
                const float dd = dd0 + dd1;
                wmax = fmaxf(wmax, dd);
                const float kp = __expf(dd - dg);
                ksum_acc += kp;
#pragma unroll
                for (int c = 0; c < 8; ++c) {
                    const float av = rl4(v0b, c & 3, r*2 + (c >> 2));
                    acc[c*4] = fmaf(kp, av, acc[c*4]);
                }
#pragma unroll
                for (int e = 0; e < 24; ++e) {
                    const float av = rl4(v1b[rq], e & 3, rr*8 + (e >> 2));
                    const int ai = (e/3)*4 + 1 + e%3;
                    acc[ai] = fmaf(kp, av, acc[ai]);
                }
            }
        }
    }
    // ---- 4-wave tree combine (same m set across waves) ----
    if (wv == 1 || wv == 3) {
        float (*rp)[34] = red[wv >> 1];
#pragma unroll
        for (int i = 0; i < 32; ++i) rp[lane][i] = acc[i];
        rp[lane][32] = ksum_acc;
        rp[lane][33] = vsum_acc;
    }
    __syncthreads();
    if (wv == 0 || wv == 2) {
        float (*rp)[34] = red[wv >> 1];
#pragma unroll
        for (int i = 0; i < 32; ++i) acc[i] += rp[lane][i];
        ksum_acc += rp[lane][32];
        vsum_acc += rp[lane][33];
    }
    __syncthreads();
    if (wv == 2) {
#pragma unroll
        for (int i = 0; i < 32; ++i) red[0][lane][i] = acc[i];
        red[0][lane][32] = ksum_acc;
        red[0][lane][33] = vsum_acc;
    }
    __syncthreads();
    if (wv == 0) {
#pragma unroll
        for (int i = 0; i < 32; ++i) acc[i] += red[0][lane][i];
        ksum_acc += red[0][lane][32];
        vsum_acc += red[0][lane][33];
        float* ctxr = ws + CTXR_OFF;
#pragma unroll
        for (int c = 0; c < 8; ++c)
#pragma unroll
            for (int j = 0; j < 4; ++j)
                atomicAdd(&ctxr[((bh*8 + c)*MM + m)*4 + j], acc[c*4+j]);
        atomicAdd(ws + KSUMR_OFF + bh*MM + m, ksum_acc);
        if (mhalf == 0) {
            const int ve = lane & 31;
            const int packed = (ve < 8) ? ve*4
                                        : ((ve-8)/3)*4 + 1 + (ve-8)%3;
            atomicAdd(ws + VSUM_OFF + bh*32 + packed, vsum_acc);
        }
    }
#pragma unroll
    for (int off = 32; off; off >>= 1) wmax = fmaxf(wmax, __shfl_xor(wmax, off, 64));
    if (lane == 0) {
        unsigned u = __float_as_uint(wmax);
        u = (u & 0x80000000u) ? ~u : (u | 0x80000000u);
        atomicMax((unsigned*)(ws + GMAX_OFF), u);
    }
}

// ------- k3: row-per-lane, TWO rows per lane (R17 WIN: ~65us)
__global__ __launch_bounds__(256, 1) void k_out(const float* __restrict__ kk0,
                                                const float* __restrict__ kk1,
                                                const float* __restrict__ w,
                                                const float* __restrict__ ws,
                                                float* __restrict__ out) {
    __shared__ float ctx_s[128*36];   // [m][p], pad 36 (b128-aligned rows)
    __shared__ float wlds[128*36];    // [m][d]*DN, pad 36
    __shared__ float ksl[128];
    __shared__ __align__(16) float sS0[32];
    __shared__ float sK0;
    const int tid = threadIdx.x;
    const int bh = blockIdx.x >> 4, chunk = blockIdx.x & 15;
    const int b = bh >> 3, h = bh & 7;
    const unsigned gu = *((const unsigned*)(ws + GMAX_OFF));
    const float gm = (gu & 0x80000000u) ? __uint_as_float(gu & 0x7fffffffu)
                                        : __uint_as_float(~gu);
    const float alpha = __expf(-gm);
    const float4* ctxr4 = (const float4*)(ws + CTXR_OFF) + (size_t)bh*1024;
    const float* vsg = ws + VSUM_OFF + bh*32;
#pragma unroll
    for (int it = 0; it < 4; ++it) {
        const int i = tid + it*256;          // 0..1023 float4s, [c][m]
        const int c = i >> 7, mm2 = i & 127;
        const float4 q = ctxr4[i];
        const int p0 = c*4;
        ctx_s[mm2*36+p0+0] = RATIO*(alpha*q.x + EPSF*vsg[p0+0]);
        ctx_s[mm2*36+p0+1] = RATIO*(alpha*q.y + EPSF*vsg[p0+1]);
        ctx_s[mm2*36+p0+2] = RATIO*(alpha*q.z + EPSF*vsg[p0+2]);
        ctx_s[mm2*36+p0+3] = RATIO*(alpha*q.w + EPSF*vsg[p0+3]);
    }
    {
        const float4* w4 = (const float4*)w;
#pragma unroll
        for (int it = 0; it < 4; ++it) {
            const int i = tid + it*256;      // [m][q]
            const int mm2 = i >> 3, q = i & 7;
            float4 t = w4[i];
            t.x*=DN; t.y*=DN; t.z*=DN; t.w*=DN;
            *(float4*)&wlds[mm2*36+q*4] = t;
        }
    }
    if (tid < 128) ksl[tid] = RATIO*(alpha*ws[KSUMR_OFF + bh*MM + tid] + EPSF*(float)LL);
    __syncthreads();
    if (tid < 32) {
        float s = 0.f;
#pragma unroll 8
        for (int mm2 = 0; mm2 < 128; ++mm2) s += ctx_s[mm2*36 + tid];
        sS0[tid] = s;
    } else if (tid < 64) {
        const int p2 = tid - 32;
        float s = ksl[p2] + ksl[32+p2] + ksl[64+p2] + ksl[96+p2];
        s += __shfl_xor(s, 1); s += __shfl_xor(s, 2); s += __shfl_xor(s, 4);
        s += __shfl_xor(s, 8); s += __shfl_xor(s, 16);
        if (p2 == 0) sK0 = s;
    }
    __syncthreads();
    const int nA = b*LL + chunk*512 + tid;
    const int nB = nA + 256;
    float KA[32], KB[32];
    {
        const float4 f0 = *(const float4*)(kk0 + (size_t)nA*64 + h*8);
        const float4 f1 = *(const float4*)(kk0 + (size_t)nA*64 + h*8 + 4);
        KA[0]=f0.x; KA[1]=f0.y; KA[2]=f0.z; KA[3]=f0.w;
        KA[4]=f1.x; KA[5]=f1.y; KA[6]=f1.z; KA[7]=f1.w;
        const float4 g0 = *(const float4*)(kk0 + (size_t)nB*64 + h*8);
        const float4 g1 = *(const float4*)(kk0 + (size_t)nB*64 + h*8 + 4);
        KB[0]=g0.x; KB[1]=g0.y; KB[2]=g0.z; KB[3]=g0.w;
        KB[4]=g1.x; KB[5]=g1.y; KB[6]=g1.z; KB[7]=g1.w;
        const float4* a4 = (const float4*)(kk1 + (size_t)nA*192 + h*24);
        const float4* b4 = (const float4*)(kk1 + (size_t)nB*192 + h*24);
#pragma unroll
        for (int gq = 0; gq < 6; ++gq) {
            const float4 ga = a4[gq];
            KA[8+gq*4+0]=ga.x; KA[8+gq*4+1]=ga.y; KA[8+gq*4+2]=ga.z; KA[8+gq*4+3]=ga.w;
            const float4 gb = b4[gq];
            KB[8+gq*4+0]=gb.x; KB[8+gq*4+1]=gb.y; KB[8+gq*4+2]=gb.z; KB[8+gq*4+3]=gb.w;
        }
    }
    float dgA = 0.f, dgB = 0.f;
#pragma unroll
    for (int d = 0; d < 32; ++d) { dgA = fmaf(KA[d], KA[d], dgA); dgB = fmaf(KB[d], KB[d], dgB); }
    dgA *= 0.5f*DN*DN;  dgB *= 0.5f*DN*DN;
    float S1A[32], S1B[32];
#pragma unroll
    for (int i = 0; i < 32; ++i) { S1A[i] = 0.f; S1B[i] = 0.f; }
    float denA = 0.f, denB = 0.f, mxA = -3.4e38f, mxB = -3.4e38f;
#pragma unroll 1
    for (int m2 = 0; m2 < 128; ++m2) {
        const float* wrow = &wlds[m2*36];
        float dA0 = 0.f, dA1 = 0.f, dB0 = 0.f, dB1 = 0.f;
#pragma unroll
        for (int q = 0; q < 8; ++q) {
            const float4 wv = *(const float4*)&wrow[q*4];
            dA0 = fmaf(KA[q*4+0], wv.x, dA0);
            dB0 = fmaf(KB[q*4+0], wv.x, dB0);
            dA1 = fmaf(KA[q*4+1], wv.y, dA1);
            dB1 = fmaf(KB[q*4+1], wv.y, dB1);
            dA0 = fmaf(KA[q*4+2], wv.z, dA0);
            dB0 = fmaf(KB[q*4+2], wv.z, dB0);
            dA1 = fmaf(KA[q*4+3], wv.w, dA1);
            dB1 = fmaf(KB[q*4+3], wv.w, dB1);
        }
        const float ddA = dA0 + dA1;
        const float ddB = dB0 + dB1;
        mxA = fmaxf(mxA, ddA);
        mxB = fmaxf(mxB, ddB);
        const float EA = __expf(ddA - dgA);
        const float EB = __expf(ddB - dgB);
        denA = fmaf(EA, ksl[m2], denA);
        denB = fmaf(EB, ksl[m2], denB);
        const float* crow = &ctx_s[m2*36];
#pragma unroll
        for (int q = 0; q < 8; ++q) {
            const float4 cv = *(const float4*)&crow[q*4];
            S1A[q*4+0] = fmaf(EA, cv.x, S1A[q*4+0]);
            S1B[q*4+0] = fmaf(EB, cv.x, S1B[q*4+0]);
            S1A[q*4+1] = fmaf(EA, cv.y, S1A[q*4+1]);
            S1B[q*4+1] = fmaf(EB, cv.y, S1B[q*4+1]);
            S1A[q*4+2] = fmaf(EA, cv.z, S1A[q*4+2]);
            S1B[q*4+2] = fmaf(EB, cv.z, S1B[q*4+2]);
            S1A[q*4+3] = fmaf(EA, cv.w, S1A[q*4+3]);
            S1B[q*4+3] = fmaf(EB, cv.w, S1B[q*4+3]);
        }
    }
    const float esA = __expf(-mxA);
    const float esB = __expf(-mxB);
    const float dinvA = 1.f / fmaf(esA, denA, EPSF*sK0);
    const float dinvB = 1.f / fmaf(esB, denB, EPSF*sK0);
    float vA[32], vB[32];
#pragma unroll
    for (int q = 0; q < 8; ++q) {
        const float4 s0 = *(const float4*)&sS0[q*4];
        vA[q*4+0] = fmaf(esA, S1A[q*4+0], EPSF*s0.x)*dinvA;
        vA[q*4+1] = fmaf(esA, S1A[q*4+1], EPSF*s0.y)*dinvA;
        vA[q*4+2] = fmaf(esA, S1A[q*4+2], EPSF*s0.z)*dinvA;
        vA[q*4+3] = fmaf(esA, S1A[q*4+3], EPSF*s0.w)*dinvA;
        vB[q*4+0] = fmaf(esB, S1B[q*4+0], EPSF*s0.x)*dinvB;
        vB[q*4+1] = fmaf(esB, S1B[q*4+1], EPSF*s0.y)*dinvB;
        vB[q*4+2] = fmaf(esB, S1B[q*4+2], EPSF*s0.z)*dinvB;
        vB[q*4+3] = fmaf(esB, S1B[q*4+3], EPSF*s0.w)*dinvB;
    }
    {
        float* o0 = out + (size_t)nA*64 + h*8;
        *(float4*)(o0)     = make_float4(vA[0],  vA[4],  vA[8],  vA[12]);
        *(float4*)(o0 + 4) = make_float4(vA[16], vA[20], vA[24], vA[28]);
        float* o1 = out + (size_t)NN*64 + (size_t)nA*192 + h*24;
        *(float4*)(o1 +  0) = make_float4(vA[1],  vA[2],  vA[3],  vA[5]);
        *(float4*)(o1 +  4) = make_float4(vA[6],  vA[7],  vA[9],  vA[10]);
        *(float4*)(o1 +  8) = make_float4(vA[11], vA[13], vA[14], vA[15]);
        *(float4*)(o1 + 12) = make_float4(vA[17], vA[18], vA[19], vA[21]);
        *(float4*)(o1 + 16) = make_float4(vA[22], vA[23], vA[25], vA[26]);
        *(float4*)(o1 + 20) = make_float4(vA[27], vA[29], vA[30], vA[31]);
    }
    {
        float* o0 = out + (size_t)nB*64 + h*8;
        *(float4*)(o0)     = make_float4(vB[0],  vB[4],  vB[8],  vB[12]);
        *(float4*)(o0 + 4) = make_float4(vB[16], vB[20], vB[24], vB[28]);
        float* o1 = out + (size_t)NN*64 + (size_t)nB*192 + h*24;
        *(float4*)(o1 +  0) = make_float4(vB[1],  vB[2],  vB[3],  vB[5]);
        *(float4*)(o1 +  4) = make_float4(vB[6],  vB[7],  vB[9],  vB[10]);
        *(float4*)(o1 +  8) = make_float4(vB[11], vB[13], vB[14], vB[15]);
        *(float4*)(o1 + 12) = make_float4(vB[17], vB[18], vB[19], vB[21]);
        *(float4*)(o1 + 16) = make_float4(vB[22], vB[23], vB[25], vB[26]);
        *(float4*)(o1 + 20) = make_float4(vB[27], vB[29], vB[30], vB[31]);
    }
}

extern "C" void kernel_launch(void* const* d_in, const int* in_sizes, int n_in,
                              void* d_out, int out_size, void* d_ws, size_t ws_size,
                              hipStream_t stream) {
    const float* v0 = (const float*)d_in[0];
    const float* v1 = (const float*)d_in[1];
    const float* k0 = (const float*)d_in[2];
    const float* k1 = (const float*)d_in[3];
    const float* w  = (const float*)d_in[6];
    float* out = (float*)d_out;
    float* ws  = (float*)d_ws;
    hipMemsetAsync(ws, 0, (size_t)ZERO_FLOATS*sizeof(float), stream);
    k_ctx1<<<2048, 256, 0, stream>>>(k0, k1, v0, v1, w, ws);
    k_out <<<512, 256, 0, stream>>>(k0, k1, w, ws, out);
}

// Round 25
// 214.445 us; speedup vs baseline: 1.1370x; 1.1370x over previous
//
#include <hip/hip_runtime.h>

#define BB 4
#define HH 8
#define LL 8192
#define NN (BB*LL)
#define DDIM 32
#define MM 128

// ws layout (float offsets)
#define CTXR_OFF 0                          // 32*8*128*4 = 131072
#define KSUMR_OFF (CTXR_OFF + 32*8*MM*4)    // 4096
#define VSUM_OFF  (KSUMR_OFF + 32*MM)       // 1024
#define GMAX_OFF  (VSUM_OFF + 32*32)        // 1
#define ZERO_FLOATS (GMAX_OFF + 1)

#define DN 0.42044820762685725f             // 32^-0.25
#define RATIO 0.08838834764831845f          // 128^-0.5
#define EPSF 1e-4f

// acc update for one row (32 fmas + 6 v1 float4 loads), packed layout
#define ACC_UPDATE(kp, a0, a1, b4)                                     \
    do {                                                               \
        acc[0]  = fmaf(kp,(a0).x,acc[0]);   acc[4]  = fmaf(kp,(a0).y,acc[4]);  \
        acc[8]  = fmaf(kp,(a0).z,acc[8]);   acc[12] = fmaf(kp,(a0).w,acc[12]); \
        acc[16] = fmaf(kp,(a1).x,acc[16]);  acc[20] = fmaf(kp,(a1).y,acc[20]); \
        acc[24] = fmaf(kp,(a1).z,acc[24]);  acc[28] = fmaf(kp,(a1).w,acc[28]); \
        float4 g;                                                      \
        g = (b4)[0];                                                   \
        acc[1]=fmaf(kp,g.x,acc[1]);  acc[2]=fmaf(kp,g.y,acc[2]);       \
        acc[3]=fmaf(kp,g.z,acc[3]);  acc[5]=fmaf(kp,g.w,acc[5]);       \
        g = (b4)[1];                                                   \
        acc[6]=fmaf(kp,g.x,acc[6]);  acc[7]=fmaf(kp,g.y,acc[7]);       \
        acc[9]=fmaf(kp,g.z,acc[9]);  acc[10]=fmaf(kp,g.w,acc[10]);     \
        g = (b4)[2];                                                   \
        acc[11]=fmaf(kp,g.x,acc[11]); acc[13]=fmaf(kp,g.y,acc[13]);    \
        acc[14]=fmaf(kp,g.z,acc[14]); acc[15]=fmaf(kp,g.w,acc[15]);    \
        g = (b4)[3];                                                   \
        acc[17]=fmaf(kp,g.x,acc[17]); acc[18]=fmaf(kp,g.y,acc[18]);    \
        acc[19]=fmaf(kp,g.z,acc[19]); acc[21]=fmaf(kp,g.w,acc[21]);    \
        g = (b4)[4];                                                   \
        acc[22]=fmaf(kp,g.x,acc[22]); acc[23]=fmaf(kp,g.y,acc[23]);    \
        acc[25]=fmaf(kp,g.z,acc[25]); acc[26]=fmaf(kp,g.w,acc[26]);    \
        g = (b4)[5];                                                   \
        acc[27]=fmaf(kp,g.x,acc[27]); acc[29]=fmaf(kp,g.y,acc[29]);    \
        acc[30]=fmaf(kp,g.z,acc[30]); acc[31]=fmaf(kp,g.w,acc[31]);    \
    } while (0)

// ------- k1: BEST measured config (R13/R17/R21: 143-147us). SMEM uniform
// row loads + 2-row pairing, grid 1024.
__global__ __launch_bounds__(256, 2) void k_ctx1(const float* __restrict__ kk0,
                                                 const float* __restrict__ kk1,
                                                 const float* __restrict__ v0,
                                                 const float* __restrict__ v1,
                                                 const float* __restrict__ w,
                                                 float* __restrict__ ws) {
    __shared__ float red[2][64][34];
    const int tid = threadIdx.x;
    const int lane = tid & 63;
    const int wid  = __builtin_amdgcn_readfirstlane(tid >> 6);
    const int half = wid & 1, rgrp = wid >> 1;
    const int m = half*64 + lane;
    const int bh = blockIdx.x >> 5, chunk = blockIdx.x & 31;
    const int b = bh >> 3, h = bh & 7;
    const int n0 = b*LL + chunk*256 + rgrp*128;
    float wreg[32];                           // w * DN (DN folded into w)
    {
        const float4* w4 = (const float4*)(w + m*DDIM);
#pragma unroll
        for (int q = 0; q < 8; ++q) {
            const float4 t = w4[q];
            wreg[q*4+0]=t.x*DN; wreg[q*4+1]=t.y*DN;
            wreg[q*4+2]=t.z*DN; wreg[q*4+3]=t.w*DN;
        }
    }
    float acc[32];
#pragma unroll
    for (int i = 0; i < 32; ++i) acc[i] = 0.f;
    float ksum_acc = 0.f, vsum_acc = 0.f, wmax = -3.4e38f;
    for (int s = 0; s < 8; ++s) {
        const int nb = n0 + s*16;
        const int dr_ = lane >> 2, dq = lane & 3;
        float diagv;
        {
            const int n = nb + dr_;
            float4 da, db;
            if (dq == 0) {
                da = *(const float4*)(kk0 + (size_t)n*64 + h*8);
                db = *(const float4*)(kk0 + (size_t)n*64 + h*8 + 4);
            } else {
                const float* bp = kk1 + (size_t)n*192 + h*24 + (dq-1)*8;
                da = *(const float4*)bp; db = *(const float4*)(bp + 4);
            }
            float ss = da.x*da.x+da.y*da.y+da.z*da.z+da.w*da.w
                     + db.x*db.x+db.y*db.y+db.z*db.z+db.w*db.w;
            ss += __shfl_xor(ss, 1); ss += __shfl_xor(ss, 2);
            diagv = 0.5f*DN*DN*ss;
        }
        if (half == 0) {
            const int ve = lane & 31, vg = lane >> 5;
#pragma unroll
            for (int rr = 0; rr < 8; ++rr) {
                const int n = nb + vg*8 + rr;
                vsum_acc += (ve < 8) ? v0[(size_t)n*64 + h*8 + ve]
                                     : v1[(size_t)n*192 + h*24 + (ve-8)];
            }
        }
#pragma unroll 1
        for (int r = 0; r < 16; r += 2) {
            const int nA = nb + r, nB = nb + r + 1;
            const float dgA = __uint_as_float(
                __builtin_amdgcn_readlane(__float_as_uint(diagv), r*4));
            const float dgB = __uint_as_float(
                __builtin_amdgcn_readlane(__float_as_uint(diagv), r*4 + 4));
            float4 kA[8], kB[8];
            kA[0] = *(const float4*)(kk0 + (size_t)nA*64 + h*8);
            kA[1] = *(const float4*)(kk0 + (size_t)nA*64 + h*8 + 4);
            kB[0] = *(const float4*)(kk0 + (size_t)nB*64 + h*8);
            kB[1] = *(const float4*)(kk0 + (size_t)nB*64 + h*8 + 4);
            {
                const float4* gA4 = (const float4*)(kk1 + (size_t)nA*192 + h*24);
                const float4* gB4 = (const float4*)(kk1 + (size_t)nB*192 + h*24);
#pragma unroll
                for (int gq = 0; gq < 6; ++gq) { kA[2+gq] = gA4[gq]; kB[2+gq] = gB4[gq]; }
            }
            float ddA0 = 0.f, ddA1 = 0.f, ddB0 = 0.f, ddB1 = 0.f;
#pragma unroll
            for (int q = 0; q < 8; ++q) {
                ddA0 = fmaf(kA[q].x, wreg[q*4+0], ddA0);
                ddB0 = fmaf(kB[q].x, wreg[q*4+0], ddB0);
                ddA1 = fmaf(kA[q].y, wreg[q*4+1], ddA1);
                ddB1 = fmaf(kB[q].y, wreg[q*4+1], ddB1);
                ddA0 = fmaf(kA[q].z, wreg[q*4+2], ddA0);
                ddB0 = fmaf(kB[q].z, wreg[q*4+2], ddB0);
                ddA1 = fmaf(kA[q].w, wreg[q*4+3], ddA1);
                ddB1 = fmaf(kB[q].w, wreg[q*4+3], ddB1);
            }
            const float ddA = ddA0 + ddA1;
            const float ddB = ddB0 + ddB1;
            wmax = fmaxf(wmax, fmaxf(ddA, ddB));
            const float kpA = __expf(ddA - dgA);
            const float kpB = __expf(ddB - dgB);
            ksum_acc += kpA; ksum_acc += kpB;
            const float4 aA0 = *(const float4*)(v0 + (size_t)nA*64 + h*8);
            const float4 aA1 = *(const float4*)(v0 + (size_t)nA*64 + h*8 + 4);
            const float4 aB0 = *(const float4*)(v0 + (size_t)nB*64 + h*8);
            const float4 aB1 = *(const float4*)(v0 + (size_t)nB*64 + h*8 + 4);
            const float4* bA4 = (const float4*)(v1 + (size_t)nA*192 + h*24);
            const float4* bB4 = (const float4*)(v1 + (size_t)nB*192 + h*24);
            ACC_UPDATE(kpA, aA0, aA1, bA4);
            ACC_UPDATE(kpB, aB0, aB1, bB4);
        }
    }
    if (rgrp == 1) {
#pragma unroll
        for (int i = 0; i < 32; ++i) red[half][lane][i] = acc[i];
        red[half][lane][32] = ksum_acc;
        red[half][lane][33] = vsum_acc;
    }
    __syncthreads();
    if (rgrp == 0) {
#pragma unroll
        for (int i = 0; i < 32; ++i) acc[i] += red[half][lane][i];
        ksum_acc += red[half][lane][32];
        vsum_acc += red[half][lane][33];
        float* ctxr = ws + CTXR_OFF;
#pragma unroll
        for (int c = 0; c < 8; ++c)
#pragma unroll
            for (int j = 0; j < 4; ++j)
                atomicAdd(&ctxr[((bh*8 + c)*MM + m)*4 + j], acc[c*4+j]);
        atomicAdd(ws + KSUMR_OFF + bh*MM + m, ksum_acc);
        if (half == 0) {
            const int ve = lane & 31;
            const int packed = (ve < 8) ? ve*4
                                        : ((ve-8)/3)*4 + 1 + (ve-8)%3;
            atomicAdd(ws + VSUM_OFF + bh*32 + packed, vsum_acc);
        }
    }
#pragma unroll
    for (int off = 32; off; off >>= 1) wmax = fmaxf(wmax, __shfl_xor(wmax, off, 64));
    if (lane == 0) {
        unsigned u = __float_as_uint(wmax);
        u = (u & 0x80000000u) ? ~u : (u | 0x80000000u);
        atomicMax((unsigned*)(ws + GMAX_OFF), u);
    }
}

// ------- k3: row-per-lane, TWO rows per lane (R17 WIN: ~65us)
__global__ __launch_bounds__(256, 1) void k_out(const float* __restrict__ kk0,
                                                const float* __restrict__ kk1,
                                                const float* __restrict__ w,
                                                const float* __restrict__ ws,
                                                float* __restrict__ out) {
    __shared__ float ctx_s[128*36];   // [m][p], pad 36 (b128-aligned rows)
    __shared__ float wlds[128*36];    // [m][d]*DN, pad 36
    __shared__ float ksl[128];
    __shared__ __align__(16) float sS0[32];
    __shared__ float sK0;
    const int tid = threadIdx.x;
    const int bh = blockIdx.x >> 4, chunk = blockIdx.x & 15;
    const int b = bh >> 3, h = bh & 7;
    const unsigned gu = *((const unsigned*)(ws + GMAX_OFF));
    const float gm = (gu & 0x80000000u) ? __uint_as_float(gu & 0x7fffffffu)
                                        : __uint_as_float(~gu);
    const float alpha = __expf(-gm);
    const float4* ctxr4 = (const float4*)(ws + CTXR_OFF) + (size_t)bh*1024;
    const float* vsg = ws + VSUM_OFF + bh*32;
#pragma unroll
    for (int it = 0; it < 4; ++it) {
        const int i = tid + it*256;          // 0..1023 float4s, [c][m]
        const int c = i >> 7, mm2 = i & 127;
        const float4 q = ctxr4[i];
        const int p0 = c*4;
        ctx_s[mm2*36+p0+0] = RATIO*(alpha*q.x + EPSF*vsg[p0+0]);
        ctx_s[mm2*36+p0+1] = RATIO*(alpha*q.y + EPSF*vsg[p0+1]);
        ctx_s[mm2*36+p0+2] = RATIO*(alpha*q.z + EPSF*vsg[p0+2]);
        ctx_s[mm2*36+p0+3] = RATIO*(alpha*q.w + EPSF*vsg[p0+3]);
    }
    {
        const float4* w4 = (const float4*)w;
#pragma unroll
        for (int it = 0; it < 4; ++it) {
            const int i = tid + it*256;      // [m][q]
            const int mm2 = i >> 3, q = i & 7;
            float4 t = w4[i];
            t.x*=DN; t.y*=DN; t.z*=DN; t.w*=DN;
            *(float4*)&wlds[mm2*36+q*4] = t;
        }
    }
    if (tid < 128) ksl[tid] = RATIO*(alpha*ws[KSUMR_OFF + bh*MM + tid] + EPSF*(float)LL);
    __syncthreads();
    if (tid < 32) {
        float s = 0.f;
#pragma unroll 8
        for (int mm2 = 0; mm2 < 128; ++mm2) s += ctx_s[mm2*36 + tid];
        sS0[tid] = s;
    } else if (tid < 64) {
        const int p2 = tid - 32;
        float s = ksl[p2] + ksl[32+p2] + ksl[64+p2] + ksl[96+p2];
        s += __shfl_xor(s, 1); s += __shfl_xor(s, 2); s += __shfl_xor(s, 4);
        s += __shfl_xor(s, 8); s += __shfl_xor(s, 16);
        if (p2 == 0) sK0 = s;
    }
    __syncthreads();
    const int nA = b*LL + chunk*512 + tid;
    const int nB = nA + 256;
    float KA[32], KB[32];
    {
        const float4 f0 = *(const float4*)(kk0 + (size_t)nA*64 + h*8);
        const float4 f1 = *(const float4*)(kk0 + (size_t)nA*64 + h*8 + 4);
        KA[0]=f0.x; KA[1]=f0.y; KA[2]=f0.z; KA[3]=f0.w;
        KA[4]=f1.x; KA[5]=f1.y; KA[6]=f1.z; KA[7]=f1.w;
        const float4 g0 = *(const float4*)(kk0 + (size_t)nB*64 + h*8);
        const float4 g1 = *(const float4*)(kk0 + (size_t)nB*64 + h*8 + 4);
        KB[0]=g0.x; KB[1]=g0.y; KB[2]=g0.z; KB[3]=g0.w;
        KB[4]=g1.x; KB[5]=g1.y; KB[6]=g1.z; KB[7]=g1.w;
        const float4* a4 = (const float4*)(kk1 + (size_t)nA*192 + h*24);
        const float4* b4 = (const float4*)(kk1 + (size_t)nB*192 + h*24);
#pragma unroll
        for (int gq = 0; gq < 6; ++gq) {
            const float4 ga = a4[gq];
            KA[8+gq*4+0]=ga.x; KA[8+gq*4+1]=ga.y; KA[8+gq*4+2]=ga.z; KA[8+gq*4+3]=ga.w;
            const float4 gb = b4[gq];
            KB[8+gq*4+0]=gb.x; KB[8+gq*4+1]=gb.y; KB[8+gq*4+2]=gb.z; KB[8+gq*4+3]=gb.w;
        }
    }
    float dgA = 0.f, dgB = 0.f;
#pragma unroll
    for (int d = 0; d < 32; ++d) { dgA = fmaf(KA[d], KA[d], dgA); dgB = fmaf(KB[d], KB[d], dgB); }
    dgA *= 0.5f*DN*DN;  dgB *= 0.5f*DN*DN;
    float S1A[32], S1B[32];
#pragma unroll
    for (int i = 0; i < 32; ++i) { S1A[i] = 0.f; S1B[i] = 0.f; }
    float denA = 0.f, denB = 0.f, mxA = -3.4e38f, mxB = -3.4e38f;
#pragma unroll 1
    for (int m2 = 0; m2 < 128; ++m2) {
        const float* wrow = &wlds[m2*36];
        float dA0 = 0.f, dA1 = 0.f, dB0 = 0.f, dB1 = 0.f;
#pragma unroll
        for (int q = 0; q < 8; ++q) {
            const float4 wv = *(const float4*)&wrow[q*4];
            dA0 = fmaf(KA[q*4+0], wv.x, dA0);
            dB0 = fmaf(KB[q*4+0], wv.x, dB0);
            dA1 = fmaf(KA[q*4+1], wv.y, dA1);
            dB1 = fmaf(KB[q*4+1], wv.y, dB1);
            dA0 = fmaf(KA[q*4+2], wv.z, dA0);
            dB0 = fmaf(KB[q*4+2], wv.z, dB0);
            dA1 = fmaf(KA[q*4+3], wv.w, dA1);
            dB1 = fmaf(KB[q*4+3], wv.w, dB1);
        }
        const float ddA = dA0 + dA1;
        const float ddB = dB0 + dB1;
        mxA = fmaxf(mxA, ddA);
        mxB = fmaxf(mxB, ddB);
        const float EA = __expf(ddA - dgA);
        const float EB = __expf(ddB - dgB);
        denA = fmaf(EA, ksl[m2], denA);
        denB = fmaf(EB, ksl[m2], denB);
        const float* crow = &ctx_s[m2*36];
#pragma unroll
        for (int q = 0; q < 8; ++q) {
            const float4 cv = *(const float4*)&crow[q*4];
            S1A[q*4+0] = fmaf(EA, cv.x, S1A[q*4+0]);
            S1B[q*4+0] = fmaf(EB, cv.x, S1B[q*4+0]);
            S1A[q*4+1] = fmaf(EA, cv.y, S1A[q*4+1]);
            S1B[q*4+1] = fmaf(EB, cv.y, S1B[q*4+1]);
            S1A[q*4+2] = fmaf(EA, cv.z, S1A[q*4+2]);
            S1B[q*4+2] = fmaf(EB, cv.z, S1B[q*4+2]);
            S1A[q*4+3] = fmaf(EA, cv.w, S1A[q*4+3]);
            S1B[q*4+3] = fmaf(EB, cv.w, S1B[q*4+3]);
        }
    }
    const float esA = __expf(-mxA);
    const float esB = __expf(-mxB);
    const float dinvA = 1.f / fmaf(esA, denA, EPSF*sK0);
    const float dinvB = 1.f / fmaf(esB, denB, EPSF*sK0);
    float vA[32], vB[32];
#pragma unroll
    for (int q = 0; q < 8; ++q) {
        const float4 s0 = *(const float4*)&sS0[q*4];
        vA[q*4+0] = fmaf(esA, S1A[q*4+0], EPSF*s0.x)*dinvA;
        vA[q*4+1] = fmaf(esA, S1A[q*4+1], EPSF*s0.y)*dinvA;
        vA[q*4+2] = fmaf(esA, S1A[q*4+2], EPSF*s0.z)*dinvA;
        vA[q*4+3] = fmaf(esA, S1A[q*4+3], EPSF*s0.w)*dinvA;
        vB[q*4+0] = fmaf(esB, S1B[q*4+0], EPSF*s0.x)*dinvB;
        vB[q*4+1] = fmaf(esB, S1B[q*4+1], EPSF*s0.y)*dinvB;
        vB[q*4+2] = fmaf(esB, S1B[q*4+2], EPSF*s0.z)*dinvB;
        vB[q*4+3] = fmaf(esB, S1B[q*4+3], EPSF*s0.w)*dinvB;
    }
    {
        float* o0 = out + (size_t)nA*64 + h*8;
        *(float4*)(o0)     = make_float4(vA[0],  vA[4],  vA[8],  vA[12]);
        *(float4*)(o0 + 4) = make_float4(vA[16], vA[20], vA[24], vA[28]);
        float* o1 = out + (size_t)NN*64 + (size_t)nA*192 + h*24;
        *(float4*)(o1 +  0) = make_float4(vA[1],  vA[2],  vA[3],  vA[5]);
        *(float4*)(o1 +  4) = make_float4(vA[6],  vA[7],  vA[9],  vA[10]);
        *(float4*)(o1 +  8) = make_float4(vA[11], vA[13], vA[14], vA[15]);
        *(float4*)(o1 + 12) = make_float4(vA[17], vA[18], vA[19], vA[21]);
        *(float4*)(o1 + 16) = make_float4(vA[22], vA[23], vA[25], vA[26]);
        *(float4*)(o1 + 20) = make_float4(vA[27], vA[29], vA[30], vA[31]);
    }
    {
        float* o0 = out + (size_t)nB*64 + h*8;
        *(float4*)(o0)     = make_float4(vB[0],  vB[4],  vB[8],  vB[12]);
        *(float4*)(o0 + 4) = make_float4(vB[16], vB[20], vB[24], vB[28]);
        float* o1 = out + (size_t)NN*64 + (size_t)nB*192 + h*24;
        *(float4*)(o1 +  0) = make_float4(vB[1],  vB[2],  vB[3],  vB[5]);
        *(float4*)(o1 +  4) = make_float4(vB[6],  vB[7],  vB[9],  vB[10]);
        *(float4*)(o1 +  8) = make_float4(vB[11], vB[13], vB[14], vB[15]);
        *(float4*)(o1 + 12) = make_float4(vB[17], vB[18], vB[19], vB[21]);
        *(float4*)(o1 + 16) = make_float4(vB[22], vB[23], vB[25], vB[26]);
        *(float4*)(o1 + 20) = make_float4(vB[27], vB[29], vB[30], vB[31]);
    }
}

extern "C" void kernel_launch(void* const* d_in, const int* in_sizes, int n_in,
                              void* d_out, int out_size, void* d_ws, size_t ws_size,
                              hipStream_t stream) {
    const float* v0 = (const float*)d_in[0];
    const float* v1 = (const float*)d_in[1];
    const float* k0 = (const float*)d_in[2];
    const float* k1 = (const float*)d_in[3];
    const float* w  = (const float*)d_in[6];
    float* out = (float*)d_out;
    float* ws  = (float*)d_ws;
    hipMemsetAsync(ws, 0, (size_t)ZERO_FLOATS*sizeof(float), stream);
    k_ctx1<<<1024, 256, 0, stream>>>(k0, k1, v0, v1, w, ws);
    k_out <<<512, 256, 0, stream>>>(k0, k1, w, ws, out);
}